// Round 5
// baseline (406.581 us; speedup 1.0000x reference)
//
#include <hip/hip_runtime.h>
#include <hip/hip_cooperative_groups.h>
#include <cstdint>
#include <cmath>

namespace cg = cooperative_groups;

// Problem constants (fixed by setup_inputs)
#define NROWS 32768
#define HD    1024
#define NMOT  128
#define NCLS  16
#define KSEL  32
#define EPSV  1e-4f

typedef __attribute__((ext_vector_type(4))) float  f32x4;
typedef __attribute__((ext_vector_type(8))) __bf16 bf16x8;
typedef __attribute__((ext_vector_type(4))) __bf16 bf16x4;
typedef unsigned long long u64;

// ---- workspace layout (in float slots) ----
// wsf[0..512)          : lossP[512] — per-GEMM-block loss partials
// wsf[512..640)        : mn[128]   — motif squared norms
// wsf[1024..66560)     : mvbf — mv converted to bf16 (128x1024)
// wsf[66560..197632)   : s1k[128][512] u64 — stage-1 top-32 keys
// wsf[197632..459776)  : cd[32768][8] — per-row dist to its 8 same-class motifs
#define WS_LP   0
#define WS_MN   512
#define WS_MVBF 1024
#define WS_S1K  66560
#define WS_CD   197632
#define CAPC    256     // per-(class,2048-row-chunk) candidate cap

static __device__ __forceinline__ float dot4(float4 v) {
    return v.x * v.x + v.y * v.y + v.z * v.z + v.w * v.w;
}

static __device__ __forceinline__ bf16x4 cvt4(float4 v) {
    bf16x4 t;
    t[0] = (__bf16)v.x; t[1] = (__bf16)v.y; t[2] = (__bf16)v.z; t[3] = (__bf16)v.w;
    return t;
}

static __device__ __forceinline__ bf16x8 cvt8(float4 a, float4 b) {
    bf16x8 t;
    t[0] = (__bf16)a.x; t[1] = (__bf16)a.y; t[2] = (__bf16)a.z; t[3] = (__bf16)a.w;
    t[4] = (__bf16)b.x; t[5] = (__bf16)b.y; t[6] = (__bf16)b.z; t[7] = (__bf16)b.w;
    return t;
}

// async 16B global->LDS (DMA; LDS dest = wave-uniform base + lane*16)
static __device__ __forceinline__ void gl16(const void* g, void* l) {
    __builtin_amdgcn_global_load_lds(
        (const __attribute__((address_space(1))) void*)g,
        (__attribute__((address_space(3))) void*)l, 16, 0, 0);
}

// packed key: ascending u64 order == (value descending, index ascending)
static __device__ __forceinline__ u64 pack_key(float v, int idx) {
    unsigned int b = __float_as_uint(v);
    unsigned int mo = (b & 0x80000000u) ? ~b : (b | 0x80000000u); // ascending map
    unsigned int khi = ~mo;                                      // descending
    return ((u64)khi << 32) | (unsigned int)idx;
}

#define BM 64
#define BK 32
#define NS (HD / BK)   // 32 k-slabs

// ---------------------------------------------------------------------------
// One kernel, 4 phases, grid-wide syncs between (cooperative launch).
// phase = -1 : all phases, with cg grid syncs (cooperative path)
// phase = 0..3 : that phase only (fallback path, one kernel boundary each)
// Grid 512 x 256, exactly 2 blocks/CU co-resident (LDS 32.8KB, VGPR<=128).
// ---------------------------------------------------------------------------
__global__ __launch_bounds__(256, 2) void fused_all(
    const float* __restrict__ z, const float* __restrict__ mv,
    const int* __restrict__ y, float* __restrict__ out,
    float* __restrict__ wsf, int phase) {

    __shared__ __align__(16) char smem[32800];

    float*  lossP = wsf + WS_LP;
    float*  mn    = wsf + WS_MN;
    __bf16* mvbf  = (__bf16*)(wsf + WS_MVBF);
    u64*    s1k   = (u64*)(wsf + WS_S1K);
    float*  cd    = wsf + WS_CD;

    const int tid  = threadIdx.x;
    const int lane = tid & 63;
    const int wid  = tid >> 6;
    const int b    = blockIdx.x;
    const bool all = (phase < 0);

    // ================= phase 0: prep — mv -> bf16, motif norms ==============
    if (all || phase == 0) {
        if (b < NMOT) {
            float* red = (float*)smem;
            const int k = tid * 4;               // 256 x 4 = 1024 = HD
            float4 v = *(const float4*)&mv[(size_t)b * HD + k];
            *(bf16x4*)&mvbf[(size_t)b * HD + k] = cvt4(v);
            float s = dot4(v);
#pragma unroll
            for (int o = 1; o < 64; o <<= 1) s += __shfl_xor(s, o, 64);
            if (lane == 0) red[wid] = s;
            __syncthreads();
            if (tid == 0) mn[b] = red[0] + red[1] + red[2] + red[3];
        }
    }
    if (all) cg::this_grid().sync();

    // ================= phase 1: streaming bf16-MFMA GEMM ====================
    if (all || phase == 1) {
        char*  bs   = smem;                       // 4 x 8KB B k-slab ring
        float* redw = (float*)(smem + 32768);

        const int l15  = lane & 15;
        const int quad = lane >> 4;
        const int row0 = b * BM;
        const int myrow = row0 + wid * 16 + l15;

        const float* zrow = z + (size_t)myrow * HD + quad * 8;

        // B DMA granule map: granule g holds row r=g>>2, k-chunk q=(g&3)^((r>>1)&3)
        const int g1 = tid, g2 = tid + 256;
        const int r1 = g1 >> 2, r2 = g2 >> 2;
        const int q1 = (g1 & 3) ^ ((r1 >> 1) & 3);
        const int q2 = (g2 & 3) ^ ((r2 >> 1) & 3);
        const __bf16* bsrc1 = mvbf + r1 * HD + q1 * 8;
        const __bf16* bsrc2 = mvbf + r2 * HD + q2 * 8;
        const int bofs = l15 * 64 + ((quad ^ ((l15 >> 1) & 3)) << 4);

        float mcv[8];
#pragma unroll
        for (int j = 0; j < 8; ++j) mcv[j] = mn[j * 16 + l15];
        const int yv = y[myrow];

        f32x4 acc[8];
#pragma unroll
        for (int j = 0; j < 8; ++j) acc[j] = (f32x4){0.f, 0.f, 0.f, 0.f};
        float zsq = 0.f;
        float4 ra[2][2];

        // prologue: DMA slabs 0,1; A-ring slabs 0,1
        gl16(bsrc1,      bs + 0 * 8192 + wid * 1024);
        gl16(bsrc2,      bs + 0 * 8192 + 4096 + wid * 1024);
        gl16(bsrc1 + BK, bs + 1 * 8192 + wid * 1024);
        gl16(bsrc2 + BK, bs + 1 * 8192 + 4096 + wid * 1024);
        ra[0][0] = *(const float4*)(zrow);
        ra[0][1] = *(const float4*)(zrow + 4);
        ra[1][0] = *(const float4*)(zrow + BK);
        ra[1][1] = *(const float4*)(zrow + BK + 4);
        __builtin_amdgcn_sched_barrier(0);
        asm volatile("s_waitcnt vmcnt(6)" ::: "memory");
        __builtin_amdgcn_s_barrier();
        asm volatile("" ::: "memory");
        __builtin_amdgcn_sched_barrier(0);

        for (int it = 0; it < NS / 4; ++it) {
#pragma unroll
            for (int u = 0; u < 4; ++u) {
                const int kt = it * 4 + u;
                const int slot = u & 1;
                bf16x8 bfr[8];
#pragma unroll
                for (int j = 0; j < 8; ++j)
                    bfr[j] = *(const bf16x8*)(bs + u * 8192 + j * 1024 + bofs);
                if (kt + 2 < NS) {
                    char* d = bs + ((u + 2) & 3) * 8192 + wid * 1024;
                    gl16(bsrc1 + (kt + 2) * BK, d);
                    gl16(bsrc2 + (kt + 2) * BK, d + 4096);
                }
                bf16x8 af = cvt8(ra[slot][0], ra[slot][1]);
                zsq += dot4(ra[slot][0]) + dot4(ra[slot][1]);
                if (kt + 2 < NS) {
                    ra[slot][0] = *(const float4*)(zrow + (kt + 2) * BK);
                    ra[slot][1] = *(const float4*)(zrow + (kt + 2) * BK + 4);
                }
#pragma unroll
                for (int j = 0; j < 8; ++j)
                    acc[j] = __builtin_amdgcn_mfma_f32_16x16x32_bf16(
                        af, bfr[j], acc[j], 0, 0, 0);
                if (kt + 2 < NS) {
                    __builtin_amdgcn_sched_barrier(0);
                    asm volatile("s_waitcnt vmcnt(4) lgkmcnt(0)" ::: "memory");
                    __builtin_amdgcn_s_barrier();
                    asm volatile("" ::: "memory");
                    __builtin_amdgcn_sched_barrier(0);
                } else if (kt + 1 < NS) {
                    __builtin_amdgcn_sched_barrier(0);
                    asm volatile("s_waitcnt vmcnt(2) lgkmcnt(0)" ::: "memory");
                    __builtin_amdgcn_s_barrier();
                    asm volatile("" ::: "memory");
                    __builtin_amdgcn_sched_barrier(0);
                }
            }
        }

        // epilogue: in-register
        zsq += __shfl_xor(zsq, 16, 64);
        zsq += __shfl_xor(zsq, 32, 64);

        float znv[4]; int rcls[4];
#pragma unroll
        for (int reg = 0; reg < 4; ++reg) {
            znv[reg]  = __shfl(zsq, quad * 4 + reg, 64);
            rcls[reg] = __shfl(yv,  quad * 4 + reg, 64);
        }
        float pm[4], ns[4];
#pragma unroll
        for (int reg = 0; reg < 4; ++reg) { pm[reg] = 0.f; ns[reg] = 0.f; }

        // C/D layout: col = lane&15, row = quad*4 + reg [verified]
#pragma unroll
        for (int j = 0; j < 8; ++j) {
            const int c = j * 16 + l15;
            const float mc = mcv[j];
            const int ccls = c >> 3;
#pragma unroll
            for (int reg = 0; reg < 4; ++reg) {
                float d = znv[reg] + mc - 2.f * acc[j][reg];
                float r = (d + 1.0f) * __builtin_amdgcn_rcpf(d + EPSV);
                float r2 = r * r;
                float s = r2 * r2 * r;   // ratio^5 == exp(log(ratio)/0.2)
                if (ccls == rcls[reg]) {
                    pm[reg] = fmaxf(pm[reg], s);
                    const int row = row0 + wid * 16 + quad * 4 + reg;
                    cd[(size_t)row * 8 + (c & 7)] = d;
                } else {
                    ns[reg] += s;
                }
            }
        }
#pragma unroll
        for (int o = 1; o < 16; o <<= 1)
#pragma unroll
            for (int reg = 0; reg < 4; ++reg) {
                pm[reg] = fmaxf(pm[reg], __shfl_xor(pm[reg], o, 64));
                ns[reg] += __shfl_xor(ns[reg], o, 64);
            }
        float li = 0.f;
        if (l15 == 0) {
#pragma unroll
            for (int reg = 0; reg < 4; ++reg)
                li += logf((ns[reg] + pm[reg]) / pm[reg]);
        }
        li += __shfl_xor(li, 16, 64);
        li += __shfl_xor(li, 32, 64);
        if (lane == 0) redw[wid] = li;
        __syncthreads();
        if (tid == 0) lossP[b] = redw[0] + redw[1] + redw[2] + redw[3];
    }
    if (all) cg::this_grid().sync();

    // ================= phase 2: per-chunk top-32 ============================
    // 512 blocks = (motif j = b>>2, chunk-group g = b&3); wave w owns chunk
    // g*4+w: ballot-scan of y, cd gather, bitonic-256 in own LDS segment
    // (barriers shared in lockstep). Emits top-32 per chunk to s1k.
    if (all || phase == 2) {
        u64 (*keys4)[256]  = (u64(*)[256])smem;           // 8 KB
        int (*clist4)[CAPC] = (int(*)[CAPC])(smem + 8192); // 4 KB

        const int j2 = b >> 2, g2 = b & 3;
        const int cls2 = j2 >> 3, m8 = j2 & 7;
        const int chunk = g2 * 4 + wid;
        const int base = chunk * 2048;

        __syncthreads();   // smem reuse guard vs phase 1 (all-mode)

        int cnt = 0;
#pragma unroll
        for (int t = 0; t < 32; ++t) {
            const int i = base + t * 64 + lane;
            const bool pred = (y[i] == cls2);
            const u64 m = __ballot(pred);
            if (pred) {
                const int p = cnt + (int)__popcll(m & ((1ull << lane) - 1ull));
                if (p < CAPC) clist4[wid][p] = i;
            }
            cnt += (int)__popcll(m);
        }
        const int n = cnt < CAPC ? cnt : CAPC;
        __syncthreads();
#pragma unroll
        for (int t = 0; t < 4; ++t) {
            const int l = t * 64 + lane;
            u64 key = ~0ull;
            if (l < n) {
                const int idx = clist4[wid][l];
                key = pack_key(cd[(size_t)idx * 8 + m8], idx);
            }
            keys4[wid][l] = key;
        }
        __syncthreads();
        for (int k = 2; k <= 256; k <<= 1) {
            for (int jj = k >> 1; jj > 0; jj >>= 1) {
#pragma unroll
                for (int t = 0; t < 2; ++t) {
                    const int pid = t * 64 + lane;
                    const int i  = ((pid & ~(jj - 1)) << 1) | (pid & (jj - 1));
                    const int ix = i | jj;
                    const u64 A = keys4[wid][i], B = keys4[wid][ix];
                    const bool up = ((i & k) == 0);
                    if ((A > B) == up) { keys4[wid][i] = B; keys4[wid][ix] = A; }
                }
                __syncthreads();
            }
        }
        if (lane < KSEL)
            s1k[(size_t)j2 * 512 + chunk * KSEL + lane] = keys4[wid][lane];
    }
    if (all) cg::this_grid().sync();

    // ================= phase 3: merge + gather-mean + blend =================
    // 512 blocks = (motif j = b>>2, column quarter q = b&3). Block 0 also
    // reduces the 512 loss partials -> out[0].
    if (all || phase == 3) {
        u64*   keysM = (u64*)smem;               // 4 KB
        int*   sel   = (int*)(smem + 4096);
        float* redf  = (float*)(smem + 4096 + 128);

        const int j3 = b >> 2, q = b & 3;

        __syncthreads();   // smem reuse guard vs phase 2 (all-mode)

        if (b == 0) {
            float s = lossP[tid] + lossP[tid + 256];
#pragma unroll
            for (int o = 1; o < 64; o <<= 1) s += __shfl_xor(s, o, 64);
            if (lane == 0) redf[wid] = s;
            __syncthreads();
            if (tid == 0)
                out[0] = (redf[0] + redf[1] + redf[2] + redf[3]) * (1.0f / NROWS);
        }

        keysM[tid]       = s1k[(size_t)j3 * 512 + tid];
        keysM[tid + 256] = s1k[(size_t)j3 * 512 + 256 + tid];
        __syncthreads();

        for (int k = 2; k <= 512; k <<= 1) {
            for (int jj = k >> 1; jj > 0; jj >>= 1) {
                const int i  = ((tid & ~(jj - 1)) << 1) | (tid & (jj - 1));
                const int ix = i | jj;
                const u64 A = keysM[i], B = keysM[ix];
                const bool up = ((i & k) == 0);
                if ((A > B) == up) { keysM[i] = B; keysM[ix] = A; }
                __syncthreads();
            }
        }
        if (tid < KSEL) sel[tid] = (int)(keysM[tid] & 0xFFFFFFFFu);
        __syncthreads();

        const int h = q * 256 + tid;
        float s = 0.f;
#pragma unroll 8
        for (int r = 0; r < KSEL; ++r) s += z[(size_t)sel[r] * HD + h];
        out[1 + (size_t)j3 * HD + h] =
            0.99f * mv[(size_t)j3 * HD + h] + 0.01f * (s * (1.0f / KSEL));
    }
}

// ---------------------------------------------------------------------------
extern "C" void kernel_launch(void* const* d_in, const int* in_sizes, int n_in,
                              void* d_out, int out_size, void* d_ws, size_t ws_size,
                              hipStream_t stream) {
    const float* z  = (const float*)d_in[0];
    const float* mv = (const float*)d_in[1];
    const int*   y  = (const int*)d_in[2];
    float* out = (float*)d_out;
    float* wsf = (float*)d_ws;

    int phase = -1;
    void* kargs[6];
    kargs[0] = (void*)&z;
    kargs[1] = (void*)&mv;
    kargs[2] = (void*)&y;
    kargs[3] = (void*)&out;
    kargs[4] = (void*)&wsf;
    kargs[5] = (void*)&phase;

    hipError_t e = hipLaunchCooperativeKernel(
        (const void*)fused_all, dim3(512), dim3(256), kargs, 0, stream);
    if (e != hipSuccess) {
        (void)hipGetLastError();   // clear; fall back to 4 phase launches
        hipLaunchKernelGGL(fused_all, dim3(NMOT), dim3(256), 0, stream,
                           z, mv, y, out, wsf, 0);
        hipLaunchKernelGGL(fused_all, dim3(512), dim3(256), 0, stream,
                           z, mv, y, out, wsf, 1);
        hipLaunchKernelGGL(fused_all, dim3(512), dim3(256), 0, stream,
                           z, mv, y, out, wsf, 2);
        hipLaunchKernelGGL(fused_all, dim3(512), dim3(256), 0, stream,
                           z, mv, y, out, wsf, 3);
    }
}

// Round 6
// 263.296 us; speedup vs baseline: 1.5442x; 1.5442x over previous
//
#include <hip/hip_runtime.h>
#include <cstdint>
#include <cmath>

// Problem constants (fixed by setup_inputs)
#define NROWS 32768
#define HD    1024
#define NMOT  128
#define NCLS  16
#define KSEL  32
#define EPSV  1e-4f

typedef __attribute__((ext_vector_type(4))) float  f32x4;
typedef __attribute__((ext_vector_type(8))) __bf16 bf16x8;
typedef __attribute__((ext_vector_type(4))) __bf16 bf16x4;
typedef unsigned long long u64;

// ---- workspace layout (in float slots) ----
// wsf[0..512)          : lossP[512] — per-GEMM-block loss partials
// wsf[512..640)        : mn[128]   — motif squared norms
// wsf[1024..66560)     : mvbf — mv converted to bf16 (128x1024)
// wsf[66560..197632)   : s1k[128][512] u64 — stage-1 top-32 keys
// wsf[197632..459776)  : cd[32768][8] — per-row dist to its 8 same-class motifs
#define WS_LP   0
#define WS_MN   512
#define WS_MVBF 1024
#define WS_S1K  66560
#define WS_CD   197632
#define CAPC    256     // per-(class,2048-row-chunk) candidate cap

static __device__ __forceinline__ float dot4(float4 v) {
    return v.x * v.x + v.y * v.y + v.z * v.z + v.w * v.w;
}

static __device__ __forceinline__ bf16x4 cvt4(float4 v) {
    bf16x4 t;
    t[0] = (__bf16)v.x; t[1] = (__bf16)v.y; t[2] = (__bf16)v.z; t[3] = (__bf16)v.w;
    return t;
}

static __device__ __forceinline__ bf16x8 cvt8(float4 a, float4 b) {
    bf16x8 t;
    t[0] = (__bf16)a.x; t[1] = (__bf16)a.y; t[2] = (__bf16)a.z; t[3] = (__bf16)a.w;
    t[4] = (__bf16)b.x; t[5] = (__bf16)b.y; t[6] = (__bf16)b.z; t[7] = (__bf16)b.w;
    return t;
}

// packed key: ascending u64 order == (value descending, index ascending)
static __device__ __forceinline__ u64 pack_key(float v, int idx) {
    unsigned int b = __float_as_uint(v);
    unsigned int mo = (b & 0x80000000u) ? ~b : (b | 0x80000000u); // ascending map
    unsigned int khi = ~mo;                                      // descending
    return ((u64)khi << 32) | (unsigned int)idx;
}

// ---------------------------------------------------------------------------
// Kernel 0: prep — mv -> bf16 copy + motif squared norms. 128 blocks.
// ---------------------------------------------------------------------------
__global__ __launch_bounds__(256) void prep_k(const float* __restrict__ mv,
                                              float* __restrict__ mn,
                                              __bf16* __restrict__ mvbf) {
    const int b = blockIdx.x;
    const int tid = threadIdx.x;
    const int k = tid * 4;               // 256 threads x 4 = 1024 = HD
    float4 v = *(const float4*)&mv[(size_t)b * HD + k];
    *(bf16x4*)&mvbf[(size_t)b * HD + k] = cvt4(v);
    float s = dot4(v);
#pragma unroll
    for (int o = 1; o < 64; o <<= 1) s += __shfl_xor(s, o, 64);
    __shared__ float red[4];
    if ((tid & 63) == 0) red[tid >> 6] = s;
    __syncthreads();
    if (tid == 0) mn[b] = red[0] + red[1] + red[2] + red[3];
}

// ---------------------------------------------------------------------------
// Kernel 1: LDS-free, barrier-free streaming bf16-MFMA GEMM (z @ M^T).
//  - B (mvbf, 256 KB) is L2-resident: each wave loads its B-fragments
//    directly global->reg per k-slab (8 static base pointers, k-offset is a
//    compile-time immediate after full unroll). Register ring depth 2.
//  - A (z, L3-resident warm) direct global->reg->cvt, ring distance 2.
//  - no __shared__ tile, no s_barrier, no waitcnt games: the compiler
//    schedules loads freely across slab iterations; ~154 VGPR -> 3 waves/SIMD.
//  - epilogue fully in-register (verified in R4): dist, contrastive loss,
//    compact same-class distance write cd[N][8], per-block loss partial.
// Tile: 64 rows x 128 cols per block, 4 waves (16 rows each), grid 512.
// ---------------------------------------------------------------------------
#define BM 64
#define BK 32
#define NS (HD / BK)   // 32 k-slabs

__global__ __launch_bounds__(256, 2) void gemm_fused(
    const float* __restrict__ z, const __bf16* __restrict__ mvbf,
    const float* __restrict__ mn, float* __restrict__ cd,
    const int* __restrict__ y, float* __restrict__ lossP) {
    __shared__ float redw[4];

    const int tid  = threadIdx.x;
    const int lane = tid & 63;
    const int wid  = tid >> 6;     // wave 0..3 owns rows wid*16 .. wid*16+15
    const int l15  = lane & 15;
    const int quad = lane >> 4;
    const int row0 = blockIdx.x * BM;
    const int myrow = row0 + wid * 16 + l15;

    // A source: row myrow; per slab kt the lane reads 8 floats at k=kt*32+quad*8
    const float* zrow = z + (size_t)myrow * HD + quad * 8;

    // B sources: fragment for n-tile j is row (j*16 + l15), k=kt*32+quad*8.
    // 8 static bases; kt*64B folds into the load immediate after unroll.
    const __bf16* bbase[8];
#pragma unroll
    for (int j = 0; j < 8; ++j)
        bbase[j] = mvbf + (size_t)(j * 16 + l15) * HD + quad * 8;

    float mcv[8];
#pragma unroll
    for (int j = 0; j < 8; ++j) mcv[j] = mn[j * 16 + l15];
    const int yv = y[myrow];

    f32x4 acc[8];
#pragma unroll
    for (int j = 0; j < 8; ++j) acc[j] = (f32x4){0.f, 0.f, 0.f, 0.f};
    float zsq = 0.f;

    // register rings: B depth-2 (L2 latency), A distance-2 (L3 latency)
    bf16x8 rb[2][8];
    float4 ra[2][2];
#pragma unroll
    for (int j = 0; j < 8; ++j) rb[0][j] = *(const bf16x8*)(bbase[j]);
    ra[0][0] = *(const float4*)(zrow);
    ra[0][1] = *(const float4*)(zrow + 4);
    ra[1][0] = *(const float4*)(zrow + BK);
    ra[1][1] = *(const float4*)(zrow + BK + 4);

#pragma unroll
    for (int kt = 0; kt < NS; ++kt) {
        const int s = kt & 1;
        // consume A slab kt, then refill its slot with slab kt+2 (distance 2)
        bf16x8 af = cvt8(ra[s][0], ra[s][1]);
        zsq += dot4(ra[s][0]) + dot4(ra[s][1]);
        if (kt + 2 < NS) {
            ra[s][0] = *(const float4*)(zrow + (kt + 2) * BK);
            ra[s][1] = *(const float4*)(zrow + (kt + 2) * BK + 4);
        }
        // B prefetch slab kt+1 into the other ring slot
        if (kt + 1 < NS) {
#pragma unroll
            for (int j = 0; j < 8; ++j)
                rb[s ^ 1][j] = *(const bf16x8*)(bbase[j] + (kt + 1) * BK);
        }
        // MFMA: 16 rows x 128 cols, K=32
#pragma unroll
        for (int j = 0; j < 8; ++j)
            acc[j] = __builtin_amdgcn_mfma_f32_16x16x32_bf16(
                af, rb[s][j], acc[j], 0, 0, 0);
    }

    // ---- epilogue: in-register. reduce ||z||^2 over the 4 k-chunk lanes ----
    zsq += __shfl_xor(zsq, 16, 64);
    zsq += __shfl_xor(zsq, 32, 64);   // all lanes: ||z||^2 of row (wid*16+l15)

    float znv[4]; int rcls[4];
#pragma unroll
    for (int reg = 0; reg < 4; ++reg) {
        znv[reg]  = __shfl(zsq, quad * 4 + reg, 64);
        rcls[reg] = __shfl(yv,  quad * 4 + reg, 64);
    }
    float pm[4], ns[4];
#pragma unroll
    for (int reg = 0; reg < 4; ++reg) { pm[reg] = 0.f; ns[reg] = 0.f; }

    // C/D layout: col = lane&15 (within n-tile j), row = quad*4 + reg [verified]
#pragma unroll
    for (int j = 0; j < 8; ++j) {
        const int c = j * 16 + l15;
        const float mc = mcv[j];
        const int ccls = c >> 3;
#pragma unroll
        for (int reg = 0; reg < 4; ++reg) {
            float d = znv[reg] + mc - 2.f * acc[j][reg];
            float r = (d + 1.0f) * __builtin_amdgcn_rcpf(d + EPSV);
            float r2 = r * r;
            float s = r2 * r2 * r;   // ratio^5 == exp(log(ratio)/0.2)
            if (ccls == rcls[reg]) {
                pm[reg] = fmaxf(pm[reg], s);
                const int row = row0 + wid * 16 + quad * 4 + reg;
                cd[(size_t)row * 8 + (c & 7)] = d;
            } else {
                ns[reg] += s;
            }
        }
    }
    // reduce over the 16 column-lanes of each quad group
#pragma unroll
    for (int o = 1; o < 16; o <<= 1)
#pragma unroll
        for (int reg = 0; reg < 4; ++reg) {
            pm[reg] = fmaxf(pm[reg], __shfl_xor(pm[reg], o, 64));
            ns[reg] += __shfl_xor(ns[reg], o, 64);
        }
    float li = 0.f;
    if (l15 == 0) {
#pragma unroll
        for (int reg = 0; reg < 4; ++reg)
            li += logf((ns[reg] + pm[reg]) / pm[reg]);  // = -log(pos/(neg+pos))
    }
    li += __shfl_xor(li, 16, 64);
    li += __shfl_xor(li, 32, 64);
    if (lane == 0) redw[wid] = li;
    __syncthreads();
    if (tid == 0) lossP[blockIdx.x] = redw[0] + redw[1] + redw[2] + redw[3];
}

// ---------------------------------------------------------------------------
// Kernel 2: stage-1 top-32. One block per (motif, 2048-row chunk) = 2048
// blocks. Inline ballot-scan of y builds the candidate list (<=256), gathers
// cd, packs keys, bitonic-256 sorts (== value desc, idx asc), emits top-32.
// ---------------------------------------------------------------------------
__global__ __launch_bounds__(256) void sel1_k(const int* __restrict__ y,
                                              const float* __restrict__ cd,
                                              u64* __restrict__ s1k) {
    __shared__ u64 keys[256];
    __shared__ int clist[CAPC];
    __shared__ int cnt;

    const int bid = blockIdx.x;
    const int j = bid >> 4, chunk = bid & 15;
    const int cls = j >> 3, m8 = j & 7;
    const int tid = threadIdx.x;
    const int lane = tid & 63;

    if (tid == 0) cnt = 0;
    __syncthreads();
    const int base = chunk * 2048;
#pragma unroll
    for (int t = 0; t < 8; ++t) {
        const int i = base + t * 256 + tid;
        const bool pred = (y[i] == cls);
        const u64 m = __ballot(pred);
        int wbase = 0;
        if (lane == 0 && m) wbase = atomicAdd(&cnt, (int)__popcll(m));
        wbase = __shfl(wbase, 0, 64);
        if (pred) {
            const int p = wbase + (int)__popcll(m & ((1ull << lane) - 1ull));
            if (p < CAPC) clist[p] = i;
        }
    }
    __syncthreads();
    const int n = cnt < CAPC ? cnt : CAPC;

    u64 key = ~0ull;
    if (tid < n) {
        const int idx = clist[tid];
        key = pack_key(cd[(size_t)idx * 8 + m8], idx);
    }
    keys[tid] = key;
    __syncthreads();

    for (int k = 2; k <= 256; k <<= 1) {
        for (int jj = k >> 1; jj > 0; jj >>= 1) {
            if (tid < 128) {
                const int i  = ((tid & ~(jj - 1)) << 1) | (tid & (jj - 1));
                const int ix = i | jj;
                const u64 A = keys[i], B = keys[ix];
                const bool up = ((i & k) == 0);
                if ((A > B) == up) { keys[i] = B; keys[ix] = A; }
            }
            __syncthreads();
        }
    }
    if (tid < KSEL) s1k[(size_t)j * 512 + chunk * KSEL + tid] = keys[tid];
}

// ---------------------------------------------------------------------------
// Kernel 3: merge 16x32 stage-1 keys -> global top-32 (bitonic-512, redundant
// per column-quarter), gather-mean of selected z rows, tau-blend, write.
// 512 blocks: (motif j = b>>2, column quarter q = b&3). Block 0 also reduces
// the 512 loss partials -> out[0].
// ---------------------------------------------------------------------------
__global__ __launch_bounds__(256) void merge_k(
    const float* __restrict__ z, const float* __restrict__ mv,
    const u64* __restrict__ s1k, const float* __restrict__ lossP,
    float* __restrict__ out) {
    __shared__ u64 keys[512];
    __shared__ int sel[KSEL];
    __shared__ float redf[4];

    const int b = blockIdx.x;
    const int j = b >> 2, q = b & 3;
    const int tid = threadIdx.x;
    const int lane = tid & 63;
    const int wave = tid >> 6;

    if (b == 0) {
        float s = lossP[tid] + lossP[tid + 256];
#pragma unroll
        for (int o = 1; o < 64; o <<= 1) s += __shfl_xor(s, o, 64);
        if (lane == 0) redf[wave] = s;
        __syncthreads();
        if (tid == 0)
            out[0] = (redf[0] + redf[1] + redf[2] + redf[3]) * (1.0f / NROWS);
    }

    keys[tid]       = s1k[(size_t)j * 512 + tid];
    keys[tid + 256] = s1k[(size_t)j * 512 + 256 + tid];
    __syncthreads();

    for (int k = 2; k <= 512; k <<= 1) {
        for (int jj = k >> 1; jj > 0; jj >>= 1) {
            const int i  = ((tid & ~(jj - 1)) << 1) | (tid & (jj - 1));
            const int ix = i | jj;
            const u64 A = keys[i], B = keys[ix];
            const bool up = ((i & k) == 0);
            if ((A > B) == up) { keys[i] = B; keys[ix] = A; }
            __syncthreads();
        }
    }
    if (tid < KSEL) sel[tid] = (int)(keys[tid] & 0xFFFFFFFFu);
    __syncthreads();

    const int h = q * 256 + tid;
    float s = 0.f;
#pragma unroll 8
    for (int r = 0; r < KSEL; ++r) s += z[(size_t)sel[r] * HD + h];
    out[1 + (size_t)j * HD + h] =
        0.99f * mv[(size_t)j * HD + h] + 0.01f * (s * (1.0f / KSEL));
}

// ---------------------------------------------------------------------------
extern "C" void kernel_launch(void* const* d_in, const int* in_sizes, int n_in,
                              void* d_out, int out_size, void* d_ws, size_t ws_size,
                              hipStream_t stream) {
    const float* z  = (const float*)d_in[0];
    const float* mv = (const float*)d_in[1];
    const int*   y  = (const int*)d_in[2];
    float* out = (float*)d_out;
    float* wsf = (float*)d_ws;
    float*  lossP = wsf + WS_LP;
    float*  mn    = wsf + WS_MN;
    __bf16* mvbf  = (__bf16*)(wsf + WS_MVBF);
    u64*    s1k   = (u64*)(wsf + WS_S1K);
    float*  cd    = wsf + WS_CD;

    hipLaunchKernelGGL(prep_k,     dim3(NMOT),       dim3(256), 0, stream,
                       mv, mn, mvbf);
    hipLaunchKernelGGL(gemm_fused, dim3(NROWS / BM), dim3(256), 0, stream,
                       z, mvbf, mn, cd, y, lossP);
    hipLaunchKernelGGL(sel1_k,     dim3(NMOT * 16),  dim3(256), 0, stream,
                       y, cd, s1k);
    hipLaunchKernelGGL(merge_k,    dim3(NMOT * 4),   dim3(256), 0, stream,
                       z, mv, s1k, lossP, out);
}

// Round 8
// 229.397 us; speedup vs baseline: 1.7724x; 1.1478x over previous
//
#include <hip/hip_runtime.h>
#include <cstdint>
#include <cmath>

// Problem constants (fixed by setup_inputs)
#define NROWS 32768
#define HD    1024
#define NMOT  128
#define NCLS  16
#define KSEL  32
#define EPSV  1e-4f

typedef __attribute__((ext_vector_type(4))) float  f32x4;
typedef __attribute__((ext_vector_type(8))) __bf16 bf16x8;
typedef __attribute__((ext_vector_type(4))) __bf16 bf16x4;
typedef unsigned long long u64;

// ---- workspace layout (in float slots) ----
// wsf[0..16)           : lossP[16] — per-chunk loss partials (from sel1_k)
// wsf[512..640)        : mn[128]  — motif squared norms
// wsf[1024..66560)     : mvbf — mv converted to bf16 (128x1024)
// wsf[66560..197632)   : s1k[128][512] u64 — stage-1 top-32 keys
// wsf[197632..459776)  : cd[32768][8] — per-row dist to its 8 same-class motifs
// wsf[459776..525312)  : pns[32768][2] — per-row negative-sum partial per half
// wsf[525312..558080)  : pmr[32768] — per-row positive max (unique writer half)
#define WS_LP   0
#define WS_MN   512
#define WS_MVBF 1024
#define WS_S1K  66560
#define WS_CD   197632
#define WS_PNS  459776
#define WS_PM   525312
#define CAPC    256     // per-(class,2048-row-chunk) candidate cap

static __device__ __forceinline__ float dot4(float4 v) {
    return v.x * v.x + v.y * v.y + v.z * v.z + v.w * v.w;
}
static __device__ __forceinline__ float dot4v(f32x4 v) {
    return v[0] * v[0] + v[1] * v[1] + v[2] * v[2] + v[3] * v[3];
}

static __device__ __forceinline__ bf16x4 cvt4(float4 v) {
    bf16x4 t;
    t[0] = (__bf16)v.x; t[1] = (__bf16)v.y; t[2] = (__bf16)v.z; t[3] = (__bf16)v.w;
    return t;
}

static __device__ __forceinline__ bf16x8 cvt8v(f32x4 a, f32x4 b) {
    bf16x8 t;
    t[0] = (__bf16)a[0]; t[1] = (__bf16)a[1]; t[2] = (__bf16)a[2]; t[3] = (__bf16)a[3];
    t[4] = (__bf16)b[0]; t[5] = (__bf16)b[1]; t[6] = (__bf16)b[2]; t[7] = (__bf16)b[3];
    return t;
}

// async 16B global->LDS (DMA; LDS dest = wave-uniform base + lane*16)
static __device__ __forceinline__ void gl16(const void* g, void* l) {
    __builtin_amdgcn_global_load_lds(
        (const __attribute__((address_space(1))) void*)g,
        (__attribute__((address_space(3))) void*)l, 16, 0, 0);
}

// unsinkable A-load: volatile asm global_load_dwordx4 with literal offset
#define LOADA(dst, base, imm)                                        \
    asm volatile("global_load_dwordx4 %0, %1, off offset:%2"         \
                 : "=&v"(dst) : "v"(base), "n"(imm))

#define WAITV6 asm volatile("s_waitcnt vmcnt(6)" ::: "memory")
#define WAITV4 asm volatile("s_waitcnt vmcnt(4)" ::: "memory")
#define WAITV2 asm volatile("s_waitcnt vmcnt(2)" ::: "memory")
#define WAITV0 asm volatile("s_waitcnt vmcnt(0)" ::: "memory")

// packed key: ascending u64 order == (value descending, index ascending)
static __device__ __forceinline__ u64 pack_key(float v, int idx) {
    unsigned int b = __float_as_uint(v);
    unsigned int mo = (b & 0x80000000u) ? ~b : (b | 0x80000000u); // ascending map
    unsigned int khi = ~mo;                                      // descending
    return ((u64)khi << 32) | (unsigned int)idx;
}

// ---------------------------------------------------------------------------
// Kernel 0: prep — mv -> bf16 copy + motif squared norms. 128 blocks.
// ---------------------------------------------------------------------------
__global__ __launch_bounds__(256) void prep_k(const float* __restrict__ mv,
                                              float* __restrict__ mn,
                                              __bf16* __restrict__ mvbf) {
    const int b = blockIdx.x;
    const int tid = threadIdx.x;
    const int k = tid * 4;               // 256 threads x 4 = 1024 = HD
    float4 v = *(const float4*)&mv[(size_t)b * HD + k];
    *(bf16x4*)&mvbf[(size_t)b * HD + k] = cvt4(v);
    float s = dot4(v);
#pragma unroll
    for (int o = 1; o < 64; o <<= 1) s += __shfl_xor(s, o, 64);
    __shared__ float red[4];
    if ((tid & 63) == 0) red[tid >> 6] = s;
    __syncthreads();
    if (tid == 0) mn[b] = red[0] + red[1] + red[2] + red[3];
}

// ---------------------------------------------------------------------------
// Kernel 1: persistent-B streaming bf16-MFMA GEMM (z @ M^T), col-half split.
//  - grid 256 blocks x 512 threads: block = (col-half h = b&1 [64 motifs],
//    row-group rg = b>>1 [256 rows]); 8 waves x 16 rows x 2 passes.
//    (R7 launched 512 blocks -> rows up to 65535 -> OOB z read -> crash.)
//  - B-half (64x1024 bf16 = 128 KB) staged ONCE into LDS in MFMA fragment
//    order via global_load_lds DMA; ONE barrier; k-loop is barrier-free.
//  - A loads are asm volatile global_load_dwordx4 (cannot be sunk by the
//    scheduler — R6's VGPR=68 proved the compiler deletes C++ reg rings),
//    ring depth 4 slabs, hand-counted s_waitcnt vmcnt(6/4/2/0) +
//    sched_barrier(0) (rule #18). B regs prefetched 1 slab ahead (lgkm auto).
//  - epilogue per half: pm (row-class in half -> unique writer) + cd, and
//    ns partial pns[row][h]; the log + reduction moved to sel1_k.
// ---------------------------------------------------------------------------
#define BK 32
#define NS (HD / BK)   // 32 k-slabs

__global__ __launch_bounds__(512, 1) void gemm_fused(
    const float* __restrict__ z, const __bf16* __restrict__ mvbf,
    const float* __restrict__ mn, float* __restrict__ cd,
    const int* __restrict__ y, float* __restrict__ pns,
    float* __restrict__ pmr) {
    __shared__ __align__(16) __bf16 Bs[65536];   // 128 KB, fragment order

    const int tid  = threadIdx.x;
    const int lane = tid & 63;
    const int wid  = tid >> 6;     // 0..7
    const int l15  = lane & 15;
    const int quad = lane >> 4;
    const int h    = blockIdx.x & 1;
    const int rg   = blockIdx.x >> 1;   // 0..127

    char* bsb = (char*)Bs;

    // ---- stage B-half once: chunk c=(kt*4+j); lane (l15,quad) holds
    //      B[h*64 + j*16 + l15][kt*32 + quad*8 .. +8)  at  bsb + c*1024 + lane*16
#pragma unroll
    for (int i = 0; i < 16; ++i) {
        const int c  = wid * 16 + i;
        const int kt = c >> 2, j = c & 3;
        const __bf16* src =
            mvbf + (size_t)(h * 64 + j * 16 + l15) * HD + kt * 32 + quad * 8;
        gl16(src, bsb + c * 1024);
    }
    __syncthreads();   // compiler emits vmcnt(0) before barrier: DMA landed

    for (int p = 0; p < 2; ++p) {
        const int rowp  = rg * 256 + p * 128;
        const int myrow = rowp + wid * 16 + l15;
        const float* zb = z + (size_t)myrow * HD + quad * 8;

        f32x4 acc[4];
#pragma unroll
        for (int j = 0; j < 4; ++j) acc[j] = (f32x4){0.f, 0.f, 0.f, 0.f};
        float zsq = 0.f;

        f32x4  ra[4][2];
        bf16x8 bfr[2][4];

        // A prologue: slabs 0..3 in flight (offsets kt*128, +16; max 3984 < 4096)
#pragma unroll
        for (int s = 0; s < 4; ++s) {
            LOADA(ra[s][0], zb, s * 128);
            LOADA(ra[s][1], zb, s * 128 + 16);
        }
        // B prefetch slab 0
#pragma unroll
        for (int j = 0; j < 4; ++j)
            bfr[0][j] = *(const bf16x8*)(bsb + j * 1024 + lane * 16);

#pragma unroll
        for (int kt = 0; kt < NS; ++kt) {
            // counted wait: slab kt's 2 loads retired; ring stays in flight.
            // (older epilogue stores only make this MORE conservative.)
            if (kt + 4 <= NS)      WAITV6;   // includes kt==NS-4 (no refill)
            else if (kt == NS - 3) WAITV4;
            else if (kt == NS - 2) WAITV2;
            else                   WAITV0;
            __builtin_amdgcn_sched_barrier(0);

            const int sl = kt & 3, cb = kt & 1;
            zsq += dot4v(ra[sl][0]) + dot4v(ra[sl][1]);
            bf16x8 af = cvt8v(ra[sl][0], ra[sl][1]);
            if (kt + 4 < NS) {
                LOADA(ra[sl][0], zb, (kt + 4) * 128);
                LOADA(ra[sl][1], zb, (kt + 4) * 128 + 16);
            }
            if (kt + 1 < NS) {
#pragma unroll
                for (int j = 0; j < 4; ++j)
                    bfr[cb ^ 1][j] = *(const bf16x8*)(
                        bsb + ((kt + 1) * 4 + j) * 1024 + lane * 16);
            }
#pragma unroll
            for (int j = 0; j < 4; ++j)
                acc[j] = __builtin_amdgcn_mfma_f32_16x16x32_bf16(
                    af, bfr[cb][j], acc[j], 0, 0, 0);
        }

        // ---- epilogue (per pass, in-register) ----
        zsq += __shfl_xor(zsq, 16, 64);
        zsq += __shfl_xor(zsq, 32, 64);   // ||z||^2 of row (wid*16+l15)
        const int yv = y[myrow];
        float mcv[4];
#pragma unroll
        for (int j = 0; j < 4; ++j) mcv[j] = mn[h * 64 + j * 16 + l15];

        float znv[4]; int rcls[4];
#pragma unroll
        for (int reg = 0; reg < 4; ++reg) {
            znv[reg]  = __shfl(zsq, quad * 4 + reg, 64);
            rcls[reg] = __shfl(yv,  quad * 4 + reg, 64);
        }
        float pm[4], ns[4];
#pragma unroll
        for (int reg = 0; reg < 4; ++reg) { pm[reg] = 0.f; ns[reg] = 0.f; }

        // C/D layout: col = lane&15 (within n-tile j), row = quad*4+reg [verified]
#pragma unroll
        for (int j = 0; j < 4; ++j) {
            const int c = h * 64 + j * 16 + l15;
            const float mc = mcv[j];
            const int ccls = c >> 3;
#pragma unroll
            for (int reg = 0; reg < 4; ++reg) {
                float d = znv[reg] + mc - 2.f * acc[j][reg];
                float r = (d + 1.0f) * __builtin_amdgcn_rcpf(d + EPSV);
                float r2 = r * r;
                float s = r2 * r2 * r;   // ratio^5 == exp(log(ratio)/0.2)
                if (ccls == rcls[reg]) {
                    pm[reg] = fmaxf(pm[reg], s);
                    const int row = rowp + wid * 16 + quad * 4 + reg;
                    cd[(size_t)row * 8 + (c & 7)] = d;
                } else {
                    ns[reg] += s;
                }
            }
        }
#pragma unroll
        for (int o = 1; o < 16; o <<= 1)
#pragma unroll
            for (int reg = 0; reg < 4; ++reg) {
                pm[reg] = fmaxf(pm[reg], __shfl_xor(pm[reg], o, 64));
                ns[reg] += __shfl_xor(ns[reg], o, 64);
            }
        if (l15 == 0) {
#pragma unroll
            for (int reg = 0; reg < 4; ++reg) {
                const int row = rowp + wid * 16 + quad * 4 + reg;
                pns[row * 2 + h] = ns[reg];
                if ((rcls[reg] >> 3) == h) pmr[row] = pm[reg];
            }
        }
        // no barrier between passes: Bs is read-only after staging
    }
}

// ---------------------------------------------------------------------------
// Kernel 2: stage-1 top-32. One block per (motif, 2048-row chunk) = 2048
// blocks. Inline ballot-scan of y builds the candidate list (<=256), gathers
// cd, packs keys, bitonic-256 sorts, emits top-32. The 16 j==0 blocks also
// compute the per-chunk contrastive-loss partial from pns/pmr.
// ---------------------------------------------------------------------------
__global__ __launch_bounds__(256) void sel1_k(const int* __restrict__ y,
                                              const float* __restrict__ cd,
                                              u64* __restrict__ s1k,
                                              const float* __restrict__ pns,
                                              const float* __restrict__ pmr,
                                              float* __restrict__ lossP) {
    __shared__ u64 keys[256];
    __shared__ int clist[CAPC];
    __shared__ int cnt;
    __shared__ float lred[4];

    const int bid = blockIdx.x;
    const int j = bid >> 4, chunk = bid & 15;
    const int cls = j >> 3, m8 = j & 7;
    const int tid = threadIdx.x;
    const int lane = tid & 63;

    if (tid == 0) cnt = 0;
    __syncthreads();
    const int base = chunk * 2048;
#pragma unroll
    for (int t = 0; t < 8; ++t) {
        const int i = base + t * 256 + tid;
        const bool pred = (y[i] == cls);
        const u64 m = __ballot(pred);
        int wbase = 0;
        if (lane == 0 && m) wbase = atomicAdd(&cnt, (int)__popcll(m));
        wbase = __shfl(wbase, 0, 64);
        if (pred) {
            const int p = wbase + (int)__popcll(m & ((1ull << lane) - 1ull));
            if (p < CAPC) clist[p] = i;
        }
    }
    __syncthreads();
    const int n = cnt < CAPC ? cnt : CAPC;

    u64 key = ~0ull;
    if (tid < n) {
        const int idx = clist[tid];
        key = pack_key(cd[(size_t)idx * 8 + m8], idx);
    }
    keys[tid] = key;
    __syncthreads();

    for (int k = 2; k <= 256; k <<= 1) {
        for (int jj = k >> 1; jj > 0; jj >>= 1) {
            if (tid < 128) {
                const int i  = ((tid & ~(jj - 1)) << 1) | (tid & (jj - 1));
                const int ix = i | jj;
                const u64 A = keys[i], B = keys[ix];
                const bool up = ((i & k) == 0);
                if ((A > B) == up) { keys[i] = B; keys[ix] = A; }
            }
            __syncthreads();
        }
    }
    if (tid < KSEL) s1k[(size_t)j * 512 + chunk * KSEL + tid] = keys[tid];

    // ---- loss partial for this chunk (j==0 blocks only; block-uniform) ----
    if (j == 0) {
        float li = 0.f;
#pragma unroll
        for (int t = 0; t < 8; ++t) {
            const int row = base + t * 256 + tid;
            const float pm = pmr[row];
            const float nst = pns[row * 2] + pns[row * 2 + 1];
            li += logf((nst + pm) / pm);   // = -log(pos/(neg+pos))
        }
#pragma unroll
        for (int o = 1; o < 64; o <<= 1) li += __shfl_xor(li, o, 64);
        if (lane == 0) lred[tid >> 6] = li;
        __syncthreads();
        if (tid == 0) lossP[chunk] = lred[0] + lred[1] + lred[2] + lred[3];
    }
}

// ---------------------------------------------------------------------------
// Kernel 3: merge 16x32 stage-1 keys -> global top-32 (bitonic-512, redundant
// per column-quarter), gather-mean of selected z rows, tau-blend, write.
// 512 blocks: (motif j = b>>2, column quarter q = b&3). Block 0 also sums the
// 16 loss partials -> out[0].
// ---------------------------------------------------------------------------
__global__ __launch_bounds__(256) void merge_k(
    const float* __restrict__ z, const float* __restrict__ mv,
    const u64* __restrict__ s1k, const float* __restrict__ lossP,
    float* __restrict__ out) {
    __shared__ u64 keys[512];
    __shared__ int sel[KSEL];

    const int b = blockIdx.x;
    const int j = b >> 2, q = b & 3;
    const int tid = threadIdx.x;

    if (b == 0 && tid < 64) {
        float li = (tid < 16) ? lossP[tid] : 0.f;
#pragma unroll
        for (int o = 1; o < 64; o <<= 1) li += __shfl_xor(li, o, 64);
        if (tid == 0) out[0] = li * (1.0f / NROWS);
    }

    keys[tid]       = s1k[(size_t)j * 512 + tid];
    keys[tid + 256] = s1k[(size_t)j * 512 + 256 + tid];
    __syncthreads();

    for (int k = 2; k <= 512; k <<= 1) {
        for (int jj = k >> 1; jj > 0; jj >>= 1) {
            const int i  = ((tid & ~(jj - 1)) << 1) | (tid & (jj - 1));
            const int ix = i | jj;
            const u64 A = keys[i], B = keys[ix];
            const bool up = ((i & k) == 0);
            if ((A > B) == up) { keys[i] = B; keys[ix] = A; }
            __syncthreads();
        }
    }
    if (tid < KSEL) sel[tid] = (int)(keys[tid] & 0xFFFFFFFFu);
    __syncthreads();

    const int h = q * 256 + tid;
    float s = 0.f;
#pragma unroll 8
    for (int r = 0; r < KSEL; ++r) s += z[(size_t)sel[r] * HD + h];
    out[1 + (size_t)j * HD + h] =
        0.99f * mv[(size_t)j * HD + h] + 0.01f * (s * (1.0f / KSEL));
}

// ---------------------------------------------------------------------------
extern "C" void kernel_launch(void* const* d_in, const int* in_sizes, int n_in,
                              void* d_out, int out_size, void* d_ws, size_t ws_size,
                              hipStream_t stream) {
    const float* z  = (const float*)d_in[0];
    const float* mv = (const float*)d_in[1];
    const int*   y  = (const int*)d_in[2];
    float* out = (float*)d_out;
    float* wsf = (float*)d_ws;
    float*  lossP = wsf + WS_LP;
    float*  mn    = wsf + WS_MN;
    __bf16* mvbf  = (__bf16*)(wsf + WS_MVBF);
    u64*    s1k   = (u64*)(wsf + WS_S1K);
    float*  cd    = wsf + WS_CD;
    float*  pns   = wsf + WS_PNS;
    float*  pmr   = wsf + WS_PM;

    hipLaunchKernelGGL(prep_k,     dim3(NMOT),      dim3(256), 0, stream,
                       mv, mn, mvbf);
    hipLaunchKernelGGL(gemm_fused, dim3(256),       dim3(512), 0, stream,
                       z, mvbf, mn, cd, y, pns, pmr);
    hipLaunchKernelGGL(sel1_k,     dim3(NMOT * 16), dim3(256), 0, stream,
                       y, cd, s1k, pns, pmr, lossP);
    hipLaunchKernelGGL(merge_k,    dim3(NMOT * 4),  dim3(256), 0, stream,
                       z, mv, s1k, lossP, out);
}